// Round 1
// 363.401 us; speedup vs baseline: 1.0133x; 1.0133x over previous
//
#include <hip/hip_runtime.h>

// LSTM, barrier-free per-wave MFMA formulation. Round 9: merged-K.
// B=4096, T=512, I=10, H=32, O=1. Gates i,f,g,o.
//
// R8 counters: MfmaUtil 60%, VALUBusy 47%, HBM 1.7%, 0 bank conflicts,
// 2 waves/SIMD. MFMA pipe is the most-loaded resource; 24 MFMAs/step with
// K-space only 74/96 used. R9 packs x_hat INTO the h_lo MFMA's K-space:
//   MFMA 1 (per tile): A = h_hi (k0..31),            B = W_hh cols 0..31
//   MFMA 2 (per tile): A = {x_hat k0..9, h_lo k10..31}, B = {W_ih | W_hh 10..31}
// -> 16 MFMAs/step (-33%), tile chain depth 3 -> 2. The h_lo low-order
// correction is dropped for channels 0..9 only (error ~3e-5/step per gate,
// forget-gate-bounded; absmax predicted ~2e-3, same as R8).
//
// Everything else identical to R8:
// - each wave owns 2 batches, all 8 gate-tiles; h round-trips through a
//   private per-wave LDS buffer (wave-ordered DS => NO barriers).
// - dense activation mapping: lane (Q=lane>>4, L=lane&15) handles one
//   (batch, hidden) pair: batch = Q>>1, hid = L + 16*(Q&1). 10 trans/lane.
// - tiles: tau = 2*gate + hhalf covers W rows 32*gate + 16*hhalf + n.
// - fp16 2-term h split (channels 10..31 keep the lo term); biases folded
//   into the sigmoid's fma (mb = scale*bias), C-init zero.
// - A layout: A[m=lane&15][k=Q*8+j]; B: B[k=Q*8+j][n=lane&15]; C: col=lane&15,
//   row=4Q+reg (verified R3-R7).
// Grid: 2048 blocks x 64 threads (1 wave/block), 2 batches/wave,
// launch_bounds(64,2) -> 2 waves/SIMD.

#define T_SZ 512
#define I_SZ 10
#define H_SZ 32

typedef _Float16 half8  __attribute__((ext_vector_type(8)));
typedef __fp16   fp16x2 __attribute__((ext_vector_type(2)));
typedef float    f32x4  __attribute__((ext_vector_type(4)));
typedef int      i32x4  __attribute__((ext_vector_type(4)));

union FH { i32x4 i; half8 h; };
static __device__ __forceinline__ half8 fragv(i32x4 v) { FH u; u.i = v; return u.h; }
static __device__ __forceinline__ half8 frag4(int a, int b, int c, int d) {
    FH u; u.i = (i32x4){a, b, c, d}; return u.h;
}

// pack 2 fp32 -> 2 fp16 in one dword (v_cvt_pkrtz_f16_f32): low = lo, high = hi
static __device__ __forceinline__ int pk16(float lo, float hi) {
    union { fp16x2 h; int i; } u;
    u.h = __builtin_amdgcn_cvt_pkrtz(lo, hi);
    return u.i;
}

#define MFMAH(A, B, C) __builtin_amdgcn_mfma_f32_16x16x32_f16((A), (B), (C), 0, 0, 0)

__global__ __launch_bounds__(64, 2)
void lstm_wave(const float* __restrict__ x, const float* __restrict__ W_ih,
               const float* __restrict__ W_hh, const float* __restrict__ b_ih,
               const float* __restrict__ b_hh, const float* __restrict__ W_dense,
               const float* __restrict__ b_dense, float* __restrict__ out)
{
    const int lane  = threadIdx.x;        // 0..63 (block = one wave)
    const int L     = lane & 15;          // A m-row / C col
    const int Q     = lane >> 4;          // k-quad
    const int bbase = blockIdx.x * 2;     // 2048 blocks x 2 batches

    const int bA   = L >> 3;              // A-side batch (rows 0-7 -> 0, 8-15 -> 1)
    const int bAct = Q >> 1;              // activation-side batch
    const int hidA = L + 16 * (Q & 1);    // activation-side hidden index

    // ---- B-fragments for all 8 tiles (one-time) ----
    // tile tau = 2*gate + hhalf: W row = 32*gate + 16*hhalf + L
    // bhh: k0..31 = W_hh cols 0..31 (pairs with h_hi A-frag)
    // bm : k0..9 = W_ih cols 0..9, k10..31 = W_hh cols 10..31 (pairs with
    //      merged {x_hat | h_lo} A-frag)
    int bhh[8][4];
    int bm[8][4];
    #pragma unroll
    for (int tau = 0; tau < 8; ++tau) {
        const int wr = 32 * (tau >> 1) + 16 * (tau & 1) + L;
        const float* ph = W_hh + wr * H_SZ + 8 * Q;
        #pragma unroll
        for (int d = 0; d < 4; ++d) {
            float2 v = *(const float2*)(ph + 2 * d);
            bhh[tau][d] = pk16(v.x, v.y);
        }
        if (Q == 0) {
            // k0..7 = W_ih cols 0..7
            const float* pi = W_ih + wr * I_SZ;
            #pragma unroll
            for (int d = 0; d < 4; ++d) {
                float2 v = *(const float2*)(pi + 2 * d);
                bm[tau][d] = pk16(v.x, v.y);
            }
        } else if (Q == 1) {
            // k8,9 = W_ih cols 8,9; k10..15 = W_hh cols 10..15
            float2 v = *(const float2*)(W_ih + wr * I_SZ + 8);
            bm[tau][0] = pk16(v.x, v.y);
            #pragma unroll
            for (int d = 1; d < 4; ++d) {
                float2 w = *(const float2*)(W_hh + wr * H_SZ + 8 + 2 * d);  // cols 10..15
                bm[tau][d] = pk16(w.x, w.y);
            }
        } else {
            // k16..31 = W_hh cols 16..31 (same as bhh on these lanes)
            bm[tau][0] = bhh[tau][0]; bm[tau][1] = bhh[tau][1];
            bm[tau][2] = bhh[tau][2]; bm[tau][3] = bhh[tau][3];
        }
    }

    // ---- biases folded into sigmoid fma: arg = scale*v + scale*bias ----
    const float nL = -1.4426950f;     // -log2(e)       (sigmoid)
    const float m2 = -2.8853901f;     // -2*log2(e)     (tanh via 2*sig(2x)-1)
    const float mbi = nL * (b_ih[hidA]          + b_hh[hidA]);
    const float mbf = nL * (b_ih[32 + hidA]     + b_hh[32 + hidA]);
    const float mbg = m2 * (b_ih[64 + hidA]     + b_hh[64 + hidA]);
    const float mbo = nL * (b_ih[96 + hidA]     + b_hh[96 + hidA]);

    // ---- per-wave LDS h buffer: [buf][plane hi/lo][batch][hid] fp16 ----
    __shared__ __attribute__((aligned(16))) _Float16 hbuf[2][2][2][H_SZ];  // 512 B
    {
        int* zz = (int*)&hbuf[0][0][0][0];
        zz[lane] = 0;                 // 128 ints total
        zz[lane + 64] = 0;
    }
    // wave-ordered DS: zeros visible to this wave's later reads, no barrier.

    // ---- x stream: 2-deep prefetch ----
    const float* xrow = x + (size_t)(bbase + bA) * (T_SZ * I_SZ);
    float2 xa0 = *(const float2*)(xrow + 0), xa1 = *(const float2*)(xrow + 2),
           xa2 = *(const float2*)(xrow + 4), xa3 = *(const float2*)(xrow + 6),
           xa4 = *(const float2*)(xrow + 8);
    float2 xb0 = *(const float2*)(xrow + I_SZ + 0), xb1 = *(const float2*)(xrow + I_SZ + 2),
           xb2 = *(const float2*)(xrow + I_SZ + 4), xb3 = *(const float2*)(xrow + I_SZ + 6),
           xb4 = *(const float2*)(xrow + I_SZ + 8);

    const f32x4 zerov = {0.f, 0.f, 0.f, 0.f};
    float cst = 0.0f;
    float hlast = 0.0f;
    const bool q0 = (Q == 0), q1 = (Q == 1);

    for (int t = 0; t < T_SZ; t += 2) {
        #pragma unroll
        for (int u = 0; u < 2; ++u) {
            const int rb = u, wb = u ^ 1;

            // h fragments from private LDS (A-frag order, broadcast reads)
            const _Float16* hp = &hbuf[rb][0][bA][8 * Q];
            const _Float16* lp = &hbuf[rb][1][bA][8 * Q];
            i32x4 hhi_ = *(const i32x4*)hp;
            i32x4 lo_  = *(const i32x4*)lp;   // h_lo channels 8Q..8Q+7

            // x_hat packs
            float2 y0 = u ? xb0 : xa0, y1 = u ? xb1 : xa1, y2 = u ? xb2 : xa2,
                   y3 = u ? xb3 : xa3, y4 = u ? xb4 : xa4;
            int p0 = pk16(y0.x, y0.y), p1 = pk16(y1.x, y1.y), p2 = pk16(y2.x, y2.y),
                p3 = pk16(y3.x, y3.y), p4 = pk16(y4.x, y4.y);

            // merged A-frag: k0..9 = x_hat, k10..31 = h_lo channels 10..31
            // (Q0: all x; Q1: dword0 = x8,x9 + h_lo 10..15; Q2/3: h_lo 16..31)
            half8 mf = fragv((i32x4){ q0 ? p0 : (q1 ? p4 : lo_[0]),
                                      q0 ? p1 : lo_[1],
                                      q0 ? p2 : lo_[2],
                                      q0 ? p3 : lo_[3] });

            // refill consumed set from t+2+u (distance-2 prefetch)
            if (t + 2 + u < T_SZ) {
                const float* xr = xrow + (t + 2 + u) * I_SZ;
                if (u == 0) {
                    xa0 = *(const float2*)(xr + 0); xa1 = *(const float2*)(xr + 2);
                    xa2 = *(const float2*)(xr + 4); xa3 = *(const float2*)(xr + 6);
                    xa4 = *(const float2*)(xr + 8);
                } else {
                    xb0 = *(const float2*)(xr + 0); xb1 = *(const float2*)(xr + 2);
                    xb2 = *(const float2*)(xr + 4); xb3 = *(const float2*)(xr + 6);
                    xb4 = *(const float2*)(xr + 8);
                }
            }

            // 8 independent 2-deep MFMA chains; keep only C reg 0 of each
            half8 hhi = fragv(hhi_);
            float v[8];
            #pragma unroll
            for (int tau = 0; tau < 8; ++tau) {
                f32x4 acc = MFMAH(mf, frag4(bm[tau][0], bm[tau][1], bm[tau][2], bm[tau][3]), zerov);
                acc = MFMAH(hhi, frag4(bhh[tau][0], bhh[tau][1], bhh[tau][2], bhh[tau][3]), acc);
                v[tau] = acc[0];
            }

            // dense activations: this lane's (batch bAct, hidden hidA)
            const bool qh = (Q & 1);
            float vi = qh ? v[1] : v[0];
            float vf = qh ? v[3] : v[2];
            float vg = qh ? v[5] : v[4];
            float vo = qh ? v[7] : v[6];
            float ig = __builtin_amdgcn_rcpf(1.0f + __builtin_amdgcn_exp2f(fmaf(nL, vi, mbi)));
            float fg = __builtin_amdgcn_rcpf(1.0f + __builtin_amdgcn_exp2f(fmaf(nL, vf, mbf)));
            float gr = __builtin_amdgcn_rcpf(1.0f + __builtin_amdgcn_exp2f(fmaf(m2, vg, mbg)));
            float gg = fmaf(2.0f, gr, -1.0f);
            float og = __builtin_amdgcn_rcpf(1.0f + __builtin_amdgcn_exp2f(fmaf(nL, vo, mbo)));
            cst = fmaf(fg, cst, ig * gg);
            float tr = __builtin_amdgcn_rcpf(1.0f + __builtin_amdgcn_exp2f(m2 * cst));
            float th = fmaf(2.0f, tr, -1.0f);
            float h  = og * th;
            hlast = h;

            // h write-back, fp16 2-term split, A-frag-order planes
            _Float16 hh = (_Float16)h;
            _Float16 hl = (_Float16)(h - (float)hh);
            hbuf[wb][0][bAct][hidA] = hh;
            hbuf[wb][1][bAct][hidA] = hl;
            // wave-ordered DS: next iteration's reads see these writes.
        }
    }

    // ---- dense head: out[b] = h . W_dense + b_dense ----
    // batch 0 lives in lanes 0-31 (Q=0,1), batch 1 in lanes 32-63 (Q=2,3)
    float v = hlast * W_dense[hidA];
    #pragma unroll
    for (int m = 16; m >= 1; m >>= 1)
        v += __shfl_xor(v, m);            // reduce within 32-lane halves
    if (lane == 0)  out[bbase + 0] = v + b_dense[0];
    if (lane == 32) out[bbase + 1] = v + b_dense[0];
}

extern "C" void kernel_launch(void* const* d_in, const int* in_sizes, int n_in,
                              void* d_out, int out_size, void* d_ws, size_t ws_size,
                              hipStream_t stream) {
    const float* x       = (const float*)d_in[0];
    const float* W_ih    = (const float*)d_in[1];
    const float* W_hh    = (const float*)d_in[2];
    const float* b_ih    = (const float*)d_in[3];
    const float* b_hh    = (const float*)d_in[4];
    const float* W_dense = (const float*)d_in[5];
    const float* b_dense = (const float*)d_in[6];
    float* out = (float*)d_out;

    // 2048 blocks x 64 threads = 2048 independent waves (2/SIMD), 2 batches each
    lstm_wave<<<dim3(2048), dim3(64), 0, stream>>>(
        x, W_ih, W_hh, b_ih, b_hh, W_dense, b_dense, out);
}